// Round 1
// baseline (810.107 us; speedup 1.0000x reference)
//
#include <hip/hip_runtime.h>
#include <math.h>

#define NNODES 50000
#define NEDGES 800000
#define DIN    256
#define DHID   128
#define NCLS   40

// ---------------- fc1: x1 = relu(X @ W1 + b1), tiled 16 nodes/block ----------
__global__ __launch_bounds__(256) void fc1_kernel(
    const float* __restrict__ X, const float* __restrict__ W1,
    const float* __restrict__ b1, float* __restrict__ x1)
{
  __shared__ float Xs[16][DIN];      // 16 KB
  const int tid   = threadIdx.x;
  const int node0 = blockIdx.x * 16;

  // cooperative load of 16 rows x 256 floats (= 1024 float4)
  const float4* Xv  = (const float4*)(X + (size_t)node0 * DIN);
  float4*       Xsv = (float4*)(&Xs[0][0]);
#pragma unroll
  for (int t = 0; t < 4; ++t) Xsv[tid + t * 256] = Xv[tid + t * 256];
  __syncthreads();

  const int h  = tid & 127;
  const int tm = tid >> 7;           // 0..1 -> node groups of 8
  float acc[8];
#pragma unroll
  for (int r = 0; r < 8; ++r) acc[r] = 0.f;

#pragma unroll 4
  for (int k = 0; k < DIN; ++k) {
    const float wv = W1[k * DHID + h];
#pragma unroll
    for (int r = 0; r < 8; ++r) acc[r] += Xs[tm * 8 + r][k] * wv;
  }
  const float bb = b1[h];
#pragma unroll
  for (int r = 0; r < 8; ++r) {
    float v = acc[r] + bb;
    x1[(size_t)(node0 + tm * 8 + r) * DHID + h] = v > 0.f ? v : 0.f;
  }
}

// ---------------- fc2: out = x3 @ W2 + b2, 8 nodes/block (320 thr) -----------
__global__ __launch_bounds__(320) void fc2_kernel(
    const float* __restrict__ x3, const float* __restrict__ W2,
    const float* __restrict__ b2, float* __restrict__ out)
{
  __shared__ float Xs[8][DHID];      // 4 KB
  const int tid   = threadIdx.x;
  const int node0 = blockIdx.x * 8;
  for (int idx = tid; idx < 8 * DHID; idx += 320)
    Xs[idx >> 7][idx & 127] = x3[(size_t)node0 * DHID + idx];
  __syncthreads();

  const int ns = tid / NCLS;         // 0..7
  const int c  = tid - ns * NCLS;    // 0..39
  float acc = b2[c];
#pragma unroll 4
  for (int k = 0; k < DHID; ++k) acc += Xs[ns][k] * W2[k * NCLS + c];
  out[(size_t)(node0 + ns) * NCLS + c] = acc;
}

// ---------------- CSR build: histogram -> scan -> scatter --------------------
__global__ void hist_kernel(const int* __restrict__ dst, int* __restrict__ deg, int e)
{
  int i = blockIdx.x * blockDim.x + threadIdx.x;
  if (i < e) atomicAdd(&deg[dst[i]], 1);
}

__global__ __launch_bounds__(1024) void scan_kernel(
    const int* __restrict__ deg, int* __restrict__ rp, int* __restrict__ cursor, int n)
{
  __shared__ int sm[1024];
  const int tid   = threadIdx.x;
  const int chunk = (n + 1023) >> 10;
  int base = tid * chunk;
  int end  = base + chunk; if (end > n) end = n;

  int s = 0;
  for (int i = base; i < end; ++i) s += deg[i];
  sm[tid] = s;
  __syncthreads();
  for (int off = 1; off < 1024; off <<= 1) {
    int t = (tid >= off) ? sm[tid - off] : 0;
    __syncthreads();
    sm[tid] += t;
    __syncthreads();
  }
  int run = sm[tid] - s;             // exclusive prefix of this chunk
  for (int i = base; i < end; ++i) {
    rp[i] = run; cursor[i] = run; run += deg[i];
  }
  if (tid == 1023) rp[n] = sm[1023];
}

__global__ void scatter_kernel(const int* __restrict__ src, const int* __restrict__ dst,
                               int* __restrict__ cursor, int* __restrict__ col, int e)
{
  int i = blockIdx.x * blockDim.x + threadIdx.x;
  if (i < e) {
    int pos = atomicAdd(&cursor[dst[i]], 1);
    col[pos] = src[i];
  }
}

// ---------------- inverse row norms ------------------------------------------
__global__ __launch_bounds__(256) void rownorm_inv_kernel(
    const float* __restrict__ x, float* __restrict__ inv, int n)
{
  const int wid  = (blockIdx.x * blockDim.x + threadIdx.x) >> 6;
  const int lane = threadIdx.x & 63;
  if (wid >= n) return;
  float2 v = *(const float2*)(x + (size_t)wid * DHID + lane * 2);
  float ss = v.x * v.x + v.y * v.y;
#pragma unroll
  for (int off = 32; off; off >>= 1) ss += __shfl_xor(ss, off);
  if (lane == 0) inv[wid] = 1.0f / fmaxf(sqrtf(ss), 1e-12f);
}

// ---------------- AGNN layer: both views, online softmax, wave/node ----------
__global__ __launch_bounds__(256) void agnn_layer_kernel(
    const float* __restrict__ x, const float* __restrict__ inv,
    const int* __restrict__ rp1, const int* __restrict__ col1,
    const int* __restrict__ rp2, const int* __restrict__ col2,
    const float* __restrict__ beta_p, const float* __restrict__ order_attn,
    float* __restrict__ y, int n)
{
  const int wid  = (blockIdx.x * blockDim.x + threadIdx.x) >> 6;
  const int lane = threadIdx.x & 63;
  if (wid >= n) return;

  const float beta = beta_p[0];
  const float invd = inv[wid];
  const float2 xd  = *(const float2*)(x + (size_t)wid * DHID + lane * 2);

  float acc0 = 0.f, acc1 = 0.f;

#pragma unroll
  for (int view = 0; view < 2; ++view) {
    const int*  rp   = view ? rp2 : rp1;
    const int*  col  = view ? col2 : col1;
    const float coef = order_attn[view];
    const int beg = rp[wid], end = rp[wid + 1];

    float m = -INFINITY, s = 0.f, y0 = 0.f, y1 = 0.f;

    int j = beg;
    for (; j + 1 < end; j += 2) {             // 2 edges in flight
      const int sa = col[j], sb = col[j + 1];
      const float2 xa = *(const float2*)(x + (size_t)sa * DHID + lane * 2);
      const float2 xb = *(const float2*)(x + (size_t)sb * DHID + lane * 2);
      float da = xa.x * xd.x + xa.y * xd.y;
      float db = xb.x * xd.x + xb.y * xd.y;
#pragma unroll
      for (int off = 32; off; off >>= 1) {
        da += __shfl_xor(da, off);
        db += __shfl_xor(db, off);
      }
      const float ea = beta * invd * inv[sa] * da;
      const float eb = beta * invd * inv[sb] * db;
      const float mnew  = fmaxf(m, fmaxf(ea, eb));
      const float scale = __expf(m - mnew);   // m=-inf on first iter -> 0
      const float wa = __expf(ea - mnew);
      const float wb = __expf(eb - mnew);
      s  = s  * scale + wa + wb;
      y0 = y0 * scale + wa * xa.x + wb * xb.x;
      y1 = y1 * scale + wa * xa.y + wb * xb.y;
      m = mnew;
    }
    if (j < end) {                            // tail edge
      const int sa = col[j];
      const float2 xa = *(const float2*)(x + (size_t)sa * DHID + lane * 2);
      float da = xa.x * xd.x + xa.y * xd.y;
#pragma unroll
      for (int off = 32; off; off >>= 1) da += __shfl_xor(da, off);
      const float ea = beta * invd * inv[sa] * da;
      const float mnew  = fmaxf(m, ea);
      const float scale = __expf(m - mnew);
      const float wa = __expf(ea - mnew);
      s  = s  * scale + wa;
      y0 = y0 * scale + wa * xa.x;
      y1 = y1 * scale + wa * xa.y;
      m = mnew;
    }
    if (end > beg) {
      const float r = coef / fmaxf(s, 1e-12f);
      acc0 += r * y0;
      acc1 += r * y1;
    }
  }
  *(float2*)(y + (size_t)wid * DHID + lane * 2) = make_float2(acc0, acc1);
}

// ---------------- launcher ----------------------------------------------------
extern "C" void kernel_launch(void* const* d_in, const int* in_sizes, int n_in,
                              void* d_out, int out_size, void* d_ws, size_t ws_size,
                              hipStream_t stream)
{
  const float* X          = (const float*)d_in[0];
  const int*   src1       = (const int*)d_in[1];
  const int*   dst1       = (const int*)d_in[2];
  const int*   src2       = (const int*)d_in[3];
  const int*   dst2       = (const int*)d_in[4];
  const float* order_attn = (const float*)d_in[5];
  const float* W1         = (const float*)d_in[6];
  const float* b1         = (const float*)d_in[7];
  const float* W2         = (const float*)d_in[8];
  const float* b2         = (const float*)d_in[9];
  const float* beta1      = (const float*)d_in[10];
  const float* beta2      = (const float*)d_in[11];
  float*       out        = (float*)d_out;

  char*  ws  = (char*)d_ws;
  size_t off = 0;
  auto alloc = [&](size_t bytes) -> void* {
    void* p = ws + off;
    off += (bytes + 255) & ~size_t(255);
    return p;
  };
  float* x1     = (float*)alloc((size_t)NNODES * DHID * 4);
  float* x2     = (float*)alloc((size_t)NNODES * DHID * 4);
  float* inv    = (float*)alloc((size_t)NNODES * 4);
  int*   rp1    = (int*)alloc((size_t)(NNODES + 1) * 4);
  int*   rp2    = (int*)alloc((size_t)(NNODES + 1) * 4);
  int*   col1   = (int*)alloc((size_t)NEDGES * 4);
  int*   col2   = (int*)alloc((size_t)NEDGES * 4);
  int*   deg    = (int*)alloc((size_t)NNODES * 4);
  int*   cursor = (int*)alloc((size_t)NNODES * 4);
  float* x3     = x1;   // x1 dead after layer1's norm -> reuse

  const int EB = (NEDGES + 255) / 256;
  const int WB = (NNODES + 3) / 4;      // 4 waves (nodes) per 256-thread block

  // CSR for both views (reused by both layers)
  hipMemsetAsync(deg, 0, NNODES * 4, stream);
  hist_kernel<<<EB, 256, 0, stream>>>(dst1, deg, NEDGES);
  scan_kernel<<<1, 1024, 0, stream>>>(deg, rp1, cursor, NNODES);
  scatter_kernel<<<EB, 256, 0, stream>>>(src1, dst1, cursor, col1, NEDGES);

  hipMemsetAsync(deg, 0, NNODES * 4, stream);
  hist_kernel<<<EB, 256, 0, stream>>>(dst2, deg, NEDGES);
  scan_kernel<<<1, 1024, 0, stream>>>(deg, rp2, cursor, NNODES);
  scatter_kernel<<<EB, 256, 0, stream>>>(src2, dst2, cursor, col2, NEDGES);

  fc1_kernel<<<NNODES / 16, 256, 0, stream>>>(X, W1, b1, x1);

  rownorm_inv_kernel<<<WB, 256, 0, stream>>>(x1, inv, NNODES);
  agnn_layer_kernel<<<WB, 256, 0, stream>>>(x1, inv, rp1, col1, rp2, col2,
                                            beta1, order_attn, x2, NNODES);
  rownorm_inv_kernel<<<WB, 256, 0, stream>>>(x2, inv, NNODES);
  agnn_layer_kernel<<<WB, 256, 0, stream>>>(x2, inv, rp1, col1, rp2, col2,
                                            beta2, order_attn, x3, NNODES);

  fc2_kernel<<<NNODES / 8, 320, 0, stream>>>(x3, W2, b2, out);
}

// Round 3
// 733.185 us; speedup vs baseline: 1.1049x; 1.1049x over previous
//
#include <hip/hip_runtime.h>
#include <math.h>

#define NNODES 50000
#define NEDGES 800000
#define DIN    256
#define DHID   128
#define NCLS   40

// ---------------- fc1: x1 = relu(X @ W1 + b1), 16 nodes/block, k by 4 --------
__global__ __launch_bounds__(256) void fc1_kernel(
    const float* __restrict__ X, const float* __restrict__ W1,
    const float* __restrict__ b1, float* __restrict__ x1)
{
  __shared__ float Xs[16][DIN];      // 16 KB
  const int tid   = threadIdx.x;
  const int node0 = blockIdx.x * 16;

  const float4* Xv  = (const float4*)(X + (size_t)node0 * DIN);
  float4*       Xsv = (float4*)(&Xs[0][0]);
#pragma unroll
  for (int t = 0; t < 4; ++t) Xsv[tid + t * 256] = Xv[tid + t * 256];
  __syncthreads();

  const int h  = tid & 127;
  const int tm = tid >> 7;           // 0..1 -> node groups of 8
  float acc[8];
#pragma unroll
  for (int r = 0; r < 8; ++r) acc[r] = 0.f;

  for (int k = 0; k < DIN; k += 4) {
    const float w0 = W1[(k + 0) * DHID + h];
    const float w1 = W1[(k + 1) * DHID + h];
    const float w2 = W1[(k + 2) * DHID + h];
    const float w3 = W1[(k + 3) * DHID + h];
#pragma unroll
    for (int r = 0; r < 8; ++r) {
      const float4 xv = *(const float4*)&Xs[tm * 8 + r][k];   // ds_read_b128 broadcast
      acc[r] += xv.x * w0 + xv.y * w1 + xv.z * w2 + xv.w * w3;
    }
  }
  const float bb = b1[h];
#pragma unroll
  for (int r = 0; r < 8; ++r) {
    float v = acc[r] + bb;
    x1[(size_t)(node0 + tm * 8 + r) * DHID + h] = v > 0.f ? v : 0.f;
  }
}

// ---------------- fc2: out = x3 @ W2 + b2, 8 nodes/block (320 thr) -----------
__global__ __launch_bounds__(320) void fc2_kernel(
    const float* __restrict__ x3, const float* __restrict__ W2,
    const float* __restrict__ b2, float* __restrict__ out)
{
  __shared__ float Xs[8][DHID];      // 4 KB
  const int tid   = threadIdx.x;
  const int node0 = blockIdx.x * 8;
  for (int idx = tid; idx < 8 * DHID; idx += 320)
    Xs[idx >> 7][idx & 127] = x3[(size_t)node0 * DHID + idx];
  __syncthreads();

  const int ns = tid / NCLS;         // 0..7
  const int c  = tid - ns * NCLS;    // 0..39
  float acc = b2[c];
#pragma unroll 8
  for (int k = 0; k < DHID; ++k) acc += Xs[ns][k] * W2[k * NCLS + c];
  out[(size_t)(node0 + ns) * NCLS + c] = acc;
}

// ---------------- CSR build (both views fused) -------------------------------
__global__ void hist2_kernel(const int* __restrict__ dst1, const int* __restrict__ dst2,
                             int* __restrict__ deg1, int* __restrict__ deg2, int e)
{
  int i = blockIdx.x * blockDim.x + threadIdx.x;
  if (i < e)            atomicAdd(&deg1[dst1[i]], 1);
  else if (i < 2 * e)   atomicAdd(&deg2[dst2[i - e]], 1);
}

__global__ __launch_bounds__(1024) void scan2_kernel(
    const int* __restrict__ deg1, const int* __restrict__ deg2,
    int* __restrict__ rp1, int* __restrict__ rp2,
    int* __restrict__ cur1, int* __restrict__ cur2, int n)
{
  const int* __restrict__ deg = blockIdx.x ? deg2 : deg1;
  int* __restrict__ rp  = blockIdx.x ? rp2  : rp1;
  int* __restrict__ cur = blockIdx.x ? cur2 : cur1;

  __shared__ int sm[1024];
  const int tid  = threadIdx.x;
  const int CH   = 52;               // 52*1024 = 53248 >= n, 52*4 B = 16B-aligned
  const int base = tid * CH;

  int s = 0;
  if (base + CH <= n) {
    const int4* dv = (const int4*)(deg + base);
#pragma unroll
    for (int q = 0; q < CH / 4; ++q) { int4 v = dv[q]; s += v.x + v.y + v.z + v.w; }
  } else {
    for (int i = base; i < n; ++i) s += deg[i];
  }
  sm[tid] = s;
  __syncthreads();
  for (int off = 1; off < 1024; off <<= 1) {
    int t = (tid >= off) ? sm[tid - off] : 0;
    __syncthreads();
    sm[tid] += t;
    __syncthreads();
  }
  int run = sm[tid] - s;             // exclusive prefix of this chunk
  const int end = (base + CH < n) ? base + CH : n;
  for (int i = base; i < end; ++i) {
    rp[i] = run; cur[i] = run; run += deg[i];
  }
  if (tid == 1023) rp[n] = sm[1023];
}

__global__ void scatter2_kernel(const int* __restrict__ src1, const int* __restrict__ dst1,
                                const int* __restrict__ src2, const int* __restrict__ dst2,
                                int* __restrict__ cur1, int* __restrict__ cur2,
                                int* __restrict__ col1, int* __restrict__ col2, int e)
{
  int i = blockIdx.x * blockDim.x + threadIdx.x;
  if (i < e) {
    int pos = atomicAdd(&cur1[dst1[i]], 1);
    col1[pos] = src1[i];
  } else if (i < 2 * e) {
    int j = i - e;
    int pos = atomicAdd(&cur2[dst2[j]], 1);
    col2[pos] = src2[j];
  }
}

// ---- canonicalize: sort each segment ascending (atomic order -> deterministic)
__global__ void sort2_kernel(const int* __restrict__ rp1, int* __restrict__ col1,
                             const int* __restrict__ rp2, int* __restrict__ col2, int n)
{
  int i = blockIdx.x * blockDim.x + threadIdx.x;
  const int* rp; int* col; int v;
  if (i < n)            { rp = rp1; col = col1; v = i; }
  else if (i < 2 * n)   { rp = rp2; col = col2; v = i - n; }
  else return;

  const int beg = rp[v], end = rp[v + 1];
  for (int a = beg + 1; a < end; ++a) {
    const int key = col[a];
    int b = a - 1;
    while (b >= beg && col[b] > key) { col[b + 1] = col[b]; --b; }
    col[b + 1] = key;
  }
}

// ---------------- inverse row norms ------------------------------------------
__global__ __launch_bounds__(256) void rownorm_inv_kernel(
    const float* __restrict__ x, float* __restrict__ inv, int n)
{
  const int wid  = (blockIdx.x * blockDim.x + threadIdx.x) >> 6;
  const int lane = threadIdx.x & 63;
  if (wid >= n) return;
  float2 v = *(const float2*)(x + (size_t)wid * DHID + lane * 2);
  float ss = v.x * v.x + v.y * v.y;
#pragma unroll
  for (int off = 32; off; off >>= 1) ss += __shfl_xor(ss, off);
  if (lane == 0) inv[wid] = 1.0f / fmaxf(sqrtf(ss), 1e-12f);
}

// ---------------- AGNN layer: wave/node, 4 edges in flight (16-lane groups) --
// softmax shift-invariance: w = exp(e) directly (|e| <= |beta|, beta=1 -> safe),
// identical to the reference's max-subtracted softmax up to fp32 rounding.
__global__ __launch_bounds__(256) void agnn_layer_kernel(
    const float* __restrict__ x, const float* __restrict__ inv,
    const int* __restrict__ rp1, const int* __restrict__ col1,
    const int* __restrict__ rp2, const int* __restrict__ col2,
    const float* __restrict__ beta_p, const float* __restrict__ order_attn,
    float* __restrict__ y_out, int n)
{
  const int wid  = (blockIdx.x * blockDim.x + threadIdx.x) >> 6;
  if (wid >= n) return;
  const int lane = threadIdx.x & 63;
  const int grp  = lane >> 4;        // 0..3  : which edge of the 4 in flight
  const int sub  = lane & 15;        // 0..15 : 8 dims each -> 128 dims

  const float beta = beta_p[0];
  const float bi   = beta * inv[wid];

  const float* xd_p = x + (size_t)wid * DHID + sub * 8;
  const float4 xd0 = *(const float4*)(xd_p);
  const float4 xd1 = *(const float4*)(xd_p + 4);

  float acc[8];
#pragma unroll
  for (int k = 0; k < 8; ++k) acc[k] = 0.f;

#pragma unroll
  for (int view = 0; view < 2; ++view) {
    const int*  rp   = view ? rp2 : rp1;
    const int*  col  = view ? col2 : col1;
    const float coef = order_attn[view];
    const int beg = rp[wid], end = rp[wid + 1];

    float s = 0.f;
    float yv[8];
#pragma unroll
    for (int k = 0; k < 8; ++k) yv[k] = 0.f;

    for (int j = beg + grp; j < end; j += 4) {
      const int   sa  = col[j];
      const float isa = inv[sa];
      const float* xs_p = x + (size_t)sa * DHID + sub * 8;
      const float4 a0 = *(const float4*)(xs_p);
      const float4 a1 = *(const float4*)(xs_p + 4);

      float d = a0.x * xd0.x + a0.y * xd0.y + a0.z * xd0.z + a0.w * xd0.w
              + a1.x * xd1.x + a1.y * xd1.y + a1.z * xd1.z + a1.w * xd1.w;
      d += __shfl_xor(d, 1);
      d += __shfl_xor(d, 2);
      d += __shfl_xor(d, 4);
      d += __shfl_xor(d, 8);

      const float w = __expf(bi * isa * d);
      s += w;
      yv[0] += w * a0.x; yv[1] += w * a0.y; yv[2] += w * a0.z; yv[3] += w * a0.w;
      yv[4] += w * a1.x; yv[5] += w * a1.y; yv[6] += w * a1.z; yv[7] += w * a1.w;
    }

    // merge the 4 group-partials (groups differ in lane bits 4..5)
    s += __shfl_xor(s, 16);
    s += __shfl_xor(s, 32);
#pragma unroll
    for (int k = 0; k < 8; ++k) {
      yv[k] += __shfl_xor(yv[k], 16);
      yv[k] += __shfl_xor(yv[k], 32);
    }
    if (end > beg) {
      const float r = coef / fmaxf(s, 1e-12f);
#pragma unroll
      for (int k = 0; k < 8; ++k) acc[k] += r * yv[k];
    }
  }

  if (grp == 0) {
    float* yp = y_out + (size_t)wid * DHID + sub * 8;
    *(float4*)(yp)     = make_float4(acc[0], acc[1], acc[2], acc[3]);
    *(float4*)(yp + 4) = make_float4(acc[4], acc[5], acc[6], acc[7]);
  }
}

// ---------------- launcher ----------------------------------------------------
extern "C" void kernel_launch(void* const* d_in, const int* in_sizes, int n_in,
                              void* d_out, int out_size, void* d_ws, size_t ws_size,
                              hipStream_t stream)
{
  const float* X          = (const float*)d_in[0];
  const int*   src1       = (const int*)d_in[1];
  const int*   dst1       = (const int*)d_in[2];
  const int*   src2       = (const int*)d_in[3];
  const int*   dst2       = (const int*)d_in[4];
  const float* order_attn = (const float*)d_in[5];
  const float* W1         = (const float*)d_in[6];
  const float* b1         = (const float*)d_in[7];
  const float* W2         = (const float*)d_in[8];
  const float* b2         = (const float*)d_in[9];
  const float* beta1      = (const float*)d_in[10];
  const float* beta2      = (const float*)d_in[11];
  float*       out        = (float*)d_out;

  char*  ws  = (char*)d_ws;
  size_t off = 0;
  auto alloc = [&](size_t bytes) -> void* {
    void* p = ws + off;
    off += (bytes + 255) & ~size_t(255);
    return p;
  };
  float* x1   = (float*)alloc((size_t)NNODES * DHID * 4);
  float* x2   = (float*)alloc((size_t)NNODES * DHID * 4);
  float* inv  = (float*)alloc((size_t)NNODES * 4);
  int*   rp1  = (int*)alloc((size_t)(NNODES + 1) * 4);
  int*   rp2  = (int*)alloc((size_t)(NNODES + 1) * 4);
  int*   col1 = (int*)alloc((size_t)NEDGES * 4);
  int*   col2 = (int*)alloc((size_t)NEDGES * 4);
  int*   deg  = (int*)alloc((size_t)2 * NNODES * 4);   // deg1 | deg2 contiguous
  int*   cur  = (int*)alloc((size_t)2 * NNODES * 4);   // cur1 | cur2 contiguous
  int*   deg1 = deg,  *deg2 = deg + NNODES;
  int*   cur1 = cur,  *cur2 = cur + NNODES;
  float* x3   = x1;   // x1 dead after layer1 -> reuse

  const int E2B = (2 * NEDGES + 255) / 256;
  const int N2B = (2 * NNODES + 255) / 256;
  const int WB  = (NNODES + 3) / 4;      // 4 waves (nodes) per 256-thread block

  // CSR for both views (reused by both layers); segments sorted so the build
  // is fully deterministic despite atomic scatter ordering.
  hipMemsetAsync(deg, 0, (size_t)2 * NNODES * 4, stream);
  hist2_kernel<<<E2B, 256, 0, stream>>>(dst1, dst2, deg1, deg2, NEDGES);
  scan2_kernel<<<2, 1024, 0, stream>>>(deg1, deg2, rp1, rp2, cur1, cur2, NNODES);
  scatter2_kernel<<<E2B, 256, 0, stream>>>(src1, dst1, src2, dst2,
                                           cur1, cur2, col1, col2, NEDGES);
  sort2_kernel<<<N2B, 256, 0, stream>>>(rp1, col1, rp2, col2, NNODES);

  fc1_kernel<<<NNODES / 16, 256, 0, stream>>>(X, W1, b1, x1);

  rownorm_inv_kernel<<<WB, 256, 0, stream>>>(x1, inv, NNODES);
  agnn_layer_kernel<<<WB, 256, 0, stream>>>(x1, inv, rp1, col1, rp2, col2,
                                            beta1, order_attn, x2, NNODES);
  rownorm_inv_kernel<<<WB, 256, 0, stream>>>(x2, inv, NNODES);
  agnn_layer_kernel<<<WB, 256, 0, stream>>>(x2, inv, rp1, col1, rp2, col2,
                                            beta2, order_attn, x3, NNODES);

  fc2_kernel<<<NNODES / 8, 320, 0, stream>>>(x3, W2, b2, out);
}